// Round 4
// baseline (384.746 us; speedup 1.0000x reference)
//
#include <hip/hip_runtime.h>
#include <hip/hip_fp16.h>
#include <math.h>

// GCN 3-layer: out = Â relu(Â relu(Â x W1 + b1) W2 + b2) W3 + b3, Â = D^-1/2(A+I)D^-1/2
// Layer 3 reordered: Â(h2 W3) = (Â h2) W3  -> aggregate in 64-dim, then GEMM 64->112.
// CSR build: ONE fused kernel (per-chunk LDS hist -> per-bucket global-atomic
// reservation -> LDS-cursor scatter into fixed-CAP bucket slots), with GEMM1
// (x W1, unscaled) fused into the same dispatch via block-range split -- GEMM1 is
// independent of the CSR chain because the dinv row-scale moved into agg1's gather.
// All dense GEMMs use v_mfma_f32_16x16x32_f16; intermediates fp16 (128B rows).

#define IN_DIM 128
#define HID 64
#define OUT_DIM 112
#define SCAN_TILE 1024   // elems per node-scan block: 256 threads x 4
#define LSHIFT 7         // 128 nodes per fine bucket
#define LMASK 127
#define MAXBUCK 1024     // supports n <= 131072
#define CHUNK 4096       // edges per scatter-chunk block
#define CAP 4096         // per-bucket slot capacity (mean fill 2046, sigma 45)

typedef _Float16 f16x8 __attribute__((ext_vector_type(8)));
typedef float f32x4 __attribute__((ext_vector_type(4)));

// ---- MFMA fp16 GEMM tile (device body, shared by standalone + fused kernels) ----
// G[r][c] = (X[r][:].W[:][c]) * (DINV?dinv[r]:1) + (BIAS?bias[c]:0)
// v_mfma_f32_16x16x32_f16; 4 waves x 16 rows = 64 rows/block.  A fragments from
// global (each element read once); W^T staged fp16 in LDS (+8-half pad).
// Layouts (verified): A/B: row|col=lane&15, k=(lane>>4)*8+j ; C/D: col=lane&15,
// row=(lane>>4)*4+reg.
template <int K, int C, bool XH, bool DINV, bool BIAS, bool OUTH>
__device__ __forceinline__ void mfma_gemm_tile(int blk, const void* __restrict__ Xv,
                                               const float* __restrict__ W,
                                               const float* __restrict__ dinv,
                                               const float* __restrict__ bias,
                                               void* __restrict__ G, int n,
                                               _Float16* Wt) {
  constexpr int KP = K + 8;       // padded LDS pitch in halves
  constexpr int NT = C / 16;      // n-tiles
  constexpr int KS = K / 32;      // k-steps
  const int tid = threadIdx.x;
  for (int idx = tid; idx < K * C; idx += 256) {
    int k = idx / C, c = idx % C;
    Wt[c * KP + k] = (_Float16)W[idx];
  }
  __syncthreads();

  const int wv = tid >> 6, l = tid & 63;
  const int rbase = blk * 64 + wv * 16;
  const int kg = (l >> 4) * 8;
  const int c16 = l & 15;

  int arow = rbase + c16;
  if (arow >= n) arow = n - 1;
  f16x8 af[KS];
  if (XH) {
    const _Float16* Xh = reinterpret_cast<const _Float16*>(Xv);
#pragma unroll
    for (int ks = 0; ks < KS; ++ks)
      af[ks] = *reinterpret_cast<const f16x8*>(&Xh[(size_t)arow * K + ks * 32 + kg]);
  } else {
    const float* Xf = reinterpret_cast<const float*>(Xv);
#pragma unroll
    for (int ks = 0; ks < KS; ++ks) {
      float4 u0 = *reinterpret_cast<const float4*>(&Xf[(size_t)arow * K + ks * 32 + kg]);
      float4 u1 = *reinterpret_cast<const float4*>(&Xf[(size_t)arow * K + ks * 32 + kg + 4]);
      f16x8 a;
      a[0] = (_Float16)u0.x; a[1] = (_Float16)u0.y; a[2] = (_Float16)u0.z; a[3] = (_Float16)u0.w;
      a[4] = (_Float16)u1.x; a[5] = (_Float16)u1.y; a[6] = (_Float16)u1.z; a[7] = (_Float16)u1.w;
      af[ks] = a;
    }
  }

  f32x4 acc[NT];
#pragma unroll
  for (int nt = 0; nt < NT; ++nt) acc[nt] = (f32x4){0.f, 0.f, 0.f, 0.f};

#pragma unroll
  for (int ks = 0; ks < KS; ++ks) {
#pragma unroll
    for (int nt = 0; nt < NT; ++nt) {
      f16x8 bf = *reinterpret_cast<const f16x8*>(&Wt[(nt * 16 + c16) * KP + ks * 32 + kg]);
      acc[nt] = __builtin_amdgcn_mfma_f32_16x16x32_f16(af[ks], bf, acc[nt], 0, 0, 0);
    }
  }

#pragma unroll
  for (int r = 0; r < 4; ++r) {
    int grow = rbase + (l >> 4) * 4 + r;
    if (grow < n) {
      float s = DINV ? dinv[grow] : 1.0f;
#pragma unroll
      for (int nt = 0; nt < NT; ++nt) {
        float v = acc[nt][r] * s;
        if (BIAS) v += bias[nt * 16 + c16];
        if (OUTH)
          reinterpret_cast<__half*>(G)[(size_t)grow * C + nt * 16 + c16] = __float2half(v);
        else
          reinterpret_cast<float*>(G)[(size_t)grow * C + nt * 16 + c16] = v;
      }
    }
  }
}

template <int K, int C, bool XH, bool DINV, bool BIAS, bool OUTH>
__global__ __launch_bounds__(256) void mfma_gemm_kernel(const void* __restrict__ Xv,
                                                        const float* __restrict__ W,
                                                        const float* __restrict__ dinv,
                                                        const float* __restrict__ bias,
                                                        void* __restrict__ G, int n) {
  __shared__ _Float16 Wt[C * (K + 8)];
  mfma_gemm_tile<K, C, XH, DINV, BIAS, OUTH>(blockIdx.x, Xv, W, dinv, bias, G, n, Wt);
}

// ---- fused: [0, nchunk) = bucket scatter chunks ; [nchunk, ...) = GEMM1 tiles ----
// Scatter: per-chunk LDS hist of coarse buckets -> one global atomicAdd per
// nonzero bucket reserves a contiguous range in that bucket's fixed-CAP slot ->
// LDS-cursor scatter writes packed (src<<7 | dst&127).  Edge-level atomics stay
// in LDS; global atomics are per-(block,bucket) only (~300K, low contention).
__global__ __launch_bounds__(256) void gemm1_scatter_kernel(
    const float* __restrict__ x, const float* __restrict__ W1, __half* __restrict__ gh,
    int n, const int* __restrict__ src, const int* __restrict__ dst,
    int* __restrict__ cur0, int* __restrict__ packed, int E, int nbuck, int nchunk) {
  __shared__ _Float16 Wt[HID * (IN_DIM + 8)];
  __shared__ int hist[MAXBUCK];
  __shared__ int cur[MAXBUCK];
  const int tid = threadIdx.x;
  if ((int)blockIdx.x < nchunk) {
    for (int i = tid; i < nbuck; i += 256) hist[i] = 0;
    __syncthreads();
    const int lo = blockIdx.x * CHUNK;
    const int hi = min(E, lo + CHUNK);
    for (int i = lo + tid; i < hi; i += 256)
      atomicAdd(&hist[dst[i] >> LSHIFT], 1);
    __syncthreads();
    for (int b = tid; b < nbuck; b += 256) {
      int c = hist[b];
      cur[b] = (c > 0) ? atomicAdd(&cur0[b], c) : 0;  // reserve [base, base+c)
    }
    __syncthreads();
    for (int i = lo + tid; i < hi; i += 256) {
      int s = src[i], d = dst[i];
      int b = d >> LSHIFT;
      int off = atomicAdd(&cur[b], 1);
      if (off < CAP) packed[b * CAP + off] = (s << LSHIFT) | (d & LMASK);
    }
  } else {
    mfma_gemm_tile<IN_DIM, HID, false, false, false, true>(
        (int)blockIdx.x - nchunk, x, W1, nullptr, nullptr, gh, n, Wt);
  }
}

// ---- per-bucket node-degree histogram -> cnt + dinv (fused) ----
__global__ __launch_bounds__(256) void fine_count_kernel(const int* __restrict__ packed,
                                                         const int* __restrict__ cur0,
                                                         int* __restrict__ cnt,
                                                         float* __restrict__ dinv, int n) {
  int b = blockIdx.x;
  __shared__ int hist[128];
  int t = threadIdx.x;
  if (t < 128) hist[t] = 0;
  __syncthreads();
  int cb = min(cur0[b], CAP);
  const int* pk = &packed[b * CAP];
  for (int e = t; e < cb; e += 256) atomicAdd(&hist[pk[e] & LMASK], 1);
  __syncthreads();
  int node = b * 128 + t;
  if (t < 128 && node < n) {
    cnt[node] = hist[t];
    dinv[node] = 1.0f / sqrtf((float)(hist[t] + 1));  // +1 = self loop
  }
}

// ---- per-bucket fill of ssrc ----
__global__ __launch_bounds__(256) void fine_scatter_kernel(const int* __restrict__ packed,
                                                           const int* __restrict__ cur0,
                                                           const int* __restrict__ row_start,
                                                           int* __restrict__ ssrc, int n) {
  int b = blockIdx.x;
  __shared__ int cur[128];
  int t = threadIdx.x;
  if (t < 128) {
    int node = b * 128 + t;
    cur[t] = (node < n) ? row_start[node] : 0;
  }
  __syncthreads();
  int cb = min(cur0[b], CAP);
  const int* pk = &packed[b * CAP];
  for (int e = t; e < cb; e += 256) {
    int p = pk[e];
    int slot = atomicAdd(&cur[p & LMASK], 1);
    ssrc[slot] = p >> LSHIFT;
  }
}

// ---- hierarchical exclusive scan over node counts -> row_start ----

__global__ __launch_bounds__(256) void scan_partial_kernel(const int* __restrict__ cnt,
                                                           int* __restrict__ blocksum,
                                                           int n) {
  int t = threadIdx.x;
  int base = blockIdx.x * SCAN_TILE + t * 4;
  int s = 0;
  if (base + 4 <= n) {
    int4 v = *reinterpret_cast<const int4*>(&cnt[base]);
    s = v.x + v.y + v.z + v.w;
  } else {
    for (int i = 0; i < 4; ++i)
      if (base + i < n) s += cnt[base + i];
  }
#pragma unroll
  for (int off = 1; off < 64; off <<= 1) s += __shfl_xor(s, off);
  __shared__ int wsum[4];
  int lane = t & 63, wv = t >> 6;
  if (lane == 0) wsum[wv] = s;
  __syncthreads();
  if (t == 0) blocksum[blockIdx.x] = wsum[0] + wsum[1] + wsum[2] + wsum[3];
}

__global__ __launch_bounds__(1024) void scan_blocksums_kernel(int* __restrict__ blocksum,
                                                              int* __restrict__ total_out,
                                                              int nb) {
  __shared__ int sh[1024];
  int t = threadIdx.x;
  int v = (t < nb) ? blocksum[t] : 0;
  sh[t] = v;
  __syncthreads();
  for (int off = 1; off < 1024; off <<= 1) {
    int u = (t >= off) ? sh[t - off] : 0;
    __syncthreads();
    sh[t] += u;
    __syncthreads();
  }
  if (t < nb) blocksum[t] = sh[t] - v;  // exclusive
  if (t == 1023) *total_out = sh[1023]; // grand total
}

__global__ __launch_bounds__(256) void scan_final_kernel(const int* __restrict__ cnt,
                                                         const int* __restrict__ blocksum,
                                                         int* __restrict__ row_start, int n) {
  int t = threadIdx.x;
  int base = blockIdx.x * SCAN_TILE + t * 4;
  int v0 = 0, v1 = 0, v2 = 0, v3 = 0;
  if (base + 4 <= n) {
    int4 v = *reinterpret_cast<const int4*>(&cnt[base]);
    v0 = v.x; v1 = v.y; v2 = v.z; v3 = v.w;
  } else {
    if (base + 0 < n) v0 = cnt[base + 0];
    if (base + 1 < n) v1 = cnt[base + 1];
    if (base + 2 < n) v2 = cnt[base + 2];
    if (base + 3 < n) v3 = cnt[base + 3];
  }
  int s = v0 + v1 + v2 + v3;
  __shared__ int sh[256];
  sh[t] = s;
  __syncthreads();
  for (int off = 1; off < 256; off <<= 1) {
    int u = (t >= off) ? sh[t - off] : 0;
    __syncthreads();
    sh[t] += u;
    __syncthreads();
  }
  int run = blocksum[blockIdx.x] + sh[t] - s;
  int p0 = run, p1 = run + v0, p2 = p1 + v1, p3 = p2 + v2;
  if (base + 4 <= n) {
    *reinterpret_cast<int4*>(&row_start[base]) = make_int4(p0, p1, p2, p3);
  } else {
    if (base + 0 < n) row_start[base + 0] = p0;
    if (base + 1 < n) row_start[base + 1] = p1;
    if (base + 2 < n) row_start[base + 2] = p2;
    if (base + 3 < n) row_start[base + 3] = p3;
  }
}

// out[d][c] = post( dinv[d]*(g[d][c]*(SRCSCALE?dinv[d]:1)
//                   + sum_e g[ssrc[e]][c]*(SRCSCALE?dinv[ssrc[e]]:1)) [+bias] )
// g fp16 (128B rows).  One wave/node; two 32-lane halves process even/odd edges;
// lane holds half2 (ch 2q,2q+1); 16 edges (4KB) in flight; fp32 accumulate;
// cross-half combine via shfl_xor(32).  SRCSCALE folds the per-source dinv scale
// into the gather (lets GEMM1 run unscaled = independent of the CSR chain).
template <int C, bool RELU, bool BIAS, bool TSCALE, bool OUTH, bool SRCSCALE>
__global__ __launch_bounds__(256) void agg_kernel(const __half* __restrict__ g,
                                                  const int* __restrict__ row_start,
                                                  const int* __restrict__ ssrc,
                                                  const float* __restrict__ dinv,
                                                  const float* __restrict__ bias,
                                                  void* __restrict__ out, int n) {
  static_assert(C == 64, "agg assumes 64 channels");
  const int tid = threadIdx.x;
  const int wv = tid >> 6;
  const int lane = tid & 63;
  const int h = lane >> 5;   // half-wave: 0 = even edges (+ self + odd tail), 1 = odd
  const int q = lane & 31;   // channel-pair index: channels {2q, 2q+1}
  int node = blockIdx.x * 4 + wv;
  if (node >= n) return;
  const __half2* g2 = reinterpret_cast<const __half2*>(g);

  int e0 = row_start[node];
  int e1 = row_start[node + 1];
  int deg = e1 - e0;
  float di = dinv[node];
  float2 acc = make_float2(0.f, 0.f);
  if (h == 0) {  // self-loop term, counted once
    float2 sv = __half22float2(g2[(size_t)node * 32 + q]);
    float w = SRCSCALE ? di : 1.0f;
    acc.x = sv.x * w; acc.y = sv.y * w;
  }
  const int pairs = deg >> 1;
  const int base = e0 + h;  // this half's first edge (stride 2)
  int k = 0;
  for (; k + 8 <= pairs; k += 8) {  // 16 edges in flight per wave
    int idx[8];
#pragma unroll
    for (int i = 0; i < 8; ++i) idx[i] = ssrc[base + 2 * (k + i)];
    __half2 v[8];
#pragma unroll
    for (int i = 0; i < 8; ++i) v[i] = g2[(size_t)idx[i] * 32 + q];
    float ds[8];
    if (SRCSCALE) {
#pragma unroll
      for (int i = 0; i < 8; ++i) ds[i] = dinv[idx[i]];
    }
#pragma unroll
    for (int i = 0; i < 8; ++i) {
      float2 f = __half22float2(v[i]);
      if (SRCSCALE) {
        acc.x = fmaf(f.x, ds[i], acc.x); acc.y = fmaf(f.y, ds[i], acc.y);
      } else {
        acc.x += f.x; acc.y += f.y;
      }
    }
  }
  for (; k < pairs; ++k) {
    int i0 = ssrc[base + 2 * k];
    float2 f = __half22float2(g2[(size_t)i0 * 32 + q]);
    float w = SRCSCALE ? dinv[i0] : 1.0f;
    acc.x = fmaf(f.x, w, acc.x); acc.y = fmaf(f.y, w, acc.y);
  }
  if ((deg & 1) && h == 0) {  // odd edge handled once, by half 0
    int i0 = ssrc[e1 - 1];
    float2 f = __half22float2(g2[(size_t)i0 * 32 + q]);
    float w = SRCSCALE ? dinv[i0] : 1.0f;
    acc.x = fmaf(f.x, w, acc.x); acc.y = fmaf(f.y, w, acc.y);
  }
  // combine even/odd halves
  acc.x += __shfl_xor(acc.x, 32);
  acc.y += __shfl_xor(acc.y, 32);

  if (h == 0) {
    float rx = acc.x * di, ry = acc.y * di;
    if (BIAS) {
      float2 bv = *reinterpret_cast<const float2*>(&bias[2 * q]);
      rx += bv.x; ry += bv.y;
    }
    if (RELU) { rx = fmaxf(rx, 0.f); ry = fmaxf(ry, 0.f); }
    if (TSCALE) { rx *= di; ry *= di; }
    if (OUTH) {
      reinterpret_cast<__half2*>(out)[(size_t)node * 32 + q] = __floats2half2_rn(rx, ry);
    } else {
      reinterpret_cast<float2*>(out)[(size_t)node * 32 + q] = make_float2(rx, ry);
    }
  }
}

extern "C" void kernel_launch(void* const* d_in, const int* in_sizes, int n_in,
                              void* d_out, int out_size, void* d_ws, size_t ws_size,
                              hipStream_t stream) {
  const float* x = (const float*)d_in[0];
  const int* ei = (const int*)d_in[1];
  const float* W1 = (const float*)d_in[2];
  const float* b1 = (const float*)d_in[3];
  const float* W2 = (const float*)d_in[4];
  const float* b2 = (const float*)d_in[5];
  const float* W3 = (const float*)d_in[6];
  const float* b3 = (const float*)d_in[7];
  float* out = (float*)d_out;

  const int n = in_sizes[0] / IN_DIM;  // 100000
  const int E = in_sizes[1] / 2;       // 1600000
  const int* src = ei;
  const int* dst = ei + E;
  const int nbuck = (n + LMASK) >> LSHIFT;        // 782
  const int nchunk = (E + CHUNK - 1) / CHUNK;     // 391

  char* p = (char*)d_ws;
  auto alloc = [&](size_t bytes) {
    char* q = p;
    p += (bytes + 255) & ~(size_t)255;
    return q;
  };
  float* dinv = (float*)alloc((size_t)n * 4);
  int* row_start = (int*)alloc((size_t)(n + 1) * 4);
  int* cnt = (int*)alloc((size_t)n * 4);
  int* blocksum = (int*)alloc((size_t)1024 * 4);
  int* cur0 = (int*)alloc((size_t)MAXBUCK * 4);
  int* packed = (int*)alloc((size_t)nbuck * CAP * 4);
  int* ssrc = (int*)alloc((size_t)E * 4);
  __half* gh  = (__half*)alloc((size_t)n * HID * 2);  // GEMM1/2 out (gather source)
  __half* h1h = (__half*)alloc((size_t)n * HID * 2);  // agg1 out = h1 (GEMM2 in); reused as z
  __half* th  = (__half*)alloc((size_t)n * HID * 2);  // agg2 out = pre-scaled t (agg3 in)
  __half* zh  = h1h;                                   // alias: h1h dead after GEMM2

  const int NB = (n + SCAN_TILE - 1) / SCAN_TILE;  // 98 node-scan blocks
  const int GGRID = (n + 63) / 64;                 // MFMA GEMM: 64 rows/block

  // ---- CSR build (fused) + GEMM1 overlapped in one dispatch ----
  hipMemsetAsync(cur0, 0, (size_t)nbuck * 4, stream);
  gemm1_scatter_kernel<<<nchunk + GGRID, 256, 0, stream>>>(x, W1, gh, n, src, dst,
                                                           cur0, packed, E, nbuck, nchunk);
  fine_count_kernel<<<nbuck, 256, 0, stream>>>(packed, cur0, cnt, dinv, n);
  scan_partial_kernel<<<NB, 256, 0, stream>>>(cnt, blocksum, n);
  scan_blocksums_kernel<<<1, 1024, 0, stream>>>(blocksum, &row_start[n], NB);
  scan_final_kernel<<<NB, 256, 0, stream>>>(cnt, blocksum, row_start, n);
  fine_scatter_kernel<<<nbuck, 256, 0, stream>>>(packed, cur0, row_start, ssrc, n);

  // ---- layer 1: h1 = relu(dinv*(Σ dinv_s g1[s] + dinv*g1[self]) + b1)  (fp16) ----
  agg_kernel<HID, true, true, false, true, true><<<(n + 3) / 4, 256, 0, stream>>>(gh, row_start, ssrc, dinv, b1, h1h, n);

  // ---- layer 2: g2=(h1 W2)*dinv_row (fp16) ; t = relu(agg*dinv + b2)*dinv (fp16) ----
  mfma_gemm_kernel<HID, HID, true, true, false, true><<<GGRID, 256, 0, stream>>>(h1h, W2, dinv, nullptr, gh, n);
  agg_kernel<HID, true, true, true, true, false><<<(n + 3) / 4, 256, 0, stream>>>(gh, row_start, ssrc, dinv, b2, th, n);

  // ---- layer 3 (reordered): z = dinv*(t + Σ t[s]) (fp16) ; out = z W3 + b3 (fp32) ----
  agg_kernel<HID, false, false, false, true, false><<<(n + 3) / 4, 256, 0, stream>>>(th, row_start, ssrc, dinv, nullptr, zh, n);
  mfma_gemm_kernel<HID, OUT_DIM, true, false, true, false><<<GGRID, 256, 0, stream>>>(zh, W3, nullptr, b3, out, n);
}

// Round 5
// 339.394 us; speedup vs baseline: 1.1336x; 1.1336x over previous
//
#include <hip/hip_runtime.h>
#include <hip/hip_fp16.h>
#include <math.h>

// GCN 3-layer: out = Â relu(Â relu(Â x W1 + b1) W2 + b2) W3 + b3, Â = D^-1/2(A+I)D^-1/2
// Layer 3 reordered: Â(h2 W3) = (Â h2) W3  -> aggregate in 64-dim, then GEMM 64->112.
// 8-dispatch pipeline (was 17 -- ~9us/gap measured):
//   memset -> K1[coarse scatter || GEMM1(x W1, unscaled)] -> K2[fine hist+scan+
//   row_start+dinv+ssrc scatter+gh row-scale, one block per bucket] ->
//   agg1 -> GEMM2 -> agg2 -> agg3 -> GEMM3
// All dense GEMMs use v_mfma_f32_16x16x32_f16; intermediates fp16 (128B rows).
// agg: R3-verified form (1 node/wave, even/odd half-waves, 16 gathers in flight);
// NO per-edge side-loads (R4 lesson: agg is L2-transaction-rate-bound).

#define IN_DIM 128
#define HID 64
#define OUT_DIM 112
#define LSHIFT 7         // 128 nodes per fine bucket
#define LMASK 127
#define MAXBUCK 1024     // supports n <= 131072
#define CHUNK 4096       // edges per scatter-chunk block
#define CAP 4096         // per-bucket slot capacity (mean fill 2046, sigma ~45)

typedef _Float16 f16x8 __attribute__((ext_vector_type(8)));
typedef float f32x4 __attribute__((ext_vector_type(4)));

// ---- MFMA fp16 GEMM tile (device body, shared by standalone + fused kernels) ----
// G[r][c] = (X[r][:].W[:][c]) * (DINV?dinv[r]:1) + (BIAS?bias[c]:0)
// v_mfma_f32_16x16x32_f16; 4 waves x 16 rows = 64 rows/block.  A fragments from
// global (each element read once); W^T staged fp16 in LDS (+8-half pad).
// Layouts (verified): A/B: row|col=lane&15, k=(lane>>4)*8+j ; C/D: col=lane&15,
// row=(lane>>4)*4+reg.
template <int K, int C, bool XH, bool DINV, bool BIAS, bool OUTH>
__device__ __forceinline__ void mfma_gemm_tile(int blk, const void* __restrict__ Xv,
                                               const float* __restrict__ W,
                                               const float* __restrict__ dinv,
                                               const float* __restrict__ bias,
                                               void* __restrict__ G, int n,
                                               _Float16* Wt) {
  constexpr int KP = K + 8;       // padded LDS pitch in halves
  constexpr int NT = C / 16;      // n-tiles
  constexpr int KS = K / 32;      // k-steps
  const int tid = threadIdx.x;
  for (int idx = tid; idx < K * C; idx += 256) {
    int k = idx / C, c = idx % C;
    Wt[c * KP + k] = (_Float16)W[idx];
  }
  __syncthreads();

  const int wv = tid >> 6, l = tid & 63;
  const int rbase = blk * 64 + wv * 16;
  const int kg = (l >> 4) * 8;
  const int c16 = l & 15;

  int arow = rbase + c16;
  if (arow >= n) arow = n - 1;
  f16x8 af[KS];
  if (XH) {
    const _Float16* Xh = reinterpret_cast<const _Float16*>(Xv);
#pragma unroll
    for (int ks = 0; ks < KS; ++ks)
      af[ks] = *reinterpret_cast<const f16x8*>(&Xh[(size_t)arow * K + ks * 32 + kg]);
  } else {
    const float* Xf = reinterpret_cast<const float*>(Xv);
#pragma unroll
    for (int ks = 0; ks < KS; ++ks) {
      float4 u0 = *reinterpret_cast<const float4*>(&Xf[(size_t)arow * K + ks * 32 + kg]);
      float4 u1 = *reinterpret_cast<const float4*>(&Xf[(size_t)arow * K + ks * 32 + kg + 4]);
      f16x8 a;
      a[0] = (_Float16)u0.x; a[1] = (_Float16)u0.y; a[2] = (_Float16)u0.z; a[3] = (_Float16)u0.w;
      a[4] = (_Float16)u1.x; a[5] = (_Float16)u1.y; a[6] = (_Float16)u1.z; a[7] = (_Float16)u1.w;
      af[ks] = a;
    }
  }

  f32x4 acc[NT];
#pragma unroll
  for (int nt = 0; nt < NT; ++nt) acc[nt] = (f32x4){0.f, 0.f, 0.f, 0.f};

#pragma unroll
  for (int ks = 0; ks < KS; ++ks) {
#pragma unroll
    for (int nt = 0; nt < NT; ++nt) {
      f16x8 bf = *reinterpret_cast<const f16x8*>(&Wt[(nt * 16 + c16) * KP + ks * 32 + kg]);
      acc[nt] = __builtin_amdgcn_mfma_f32_16x16x32_f16(af[ks], bf, acc[nt], 0, 0, 0);
    }
  }

#pragma unroll
  for (int r = 0; r < 4; ++r) {
    int grow = rbase + (l >> 4) * 4 + r;
    if (grow < n) {
      float s = DINV ? dinv[grow] : 1.0f;
#pragma unroll
      for (int nt = 0; nt < NT; ++nt) {
        float v = acc[nt][r] * s;
        if (BIAS) v += bias[nt * 16 + c16];
        if (OUTH)
          reinterpret_cast<__half*>(G)[(size_t)grow * C + nt * 16 + c16] = __float2half(v);
        else
          reinterpret_cast<float*>(G)[(size_t)grow * C + nt * 16 + c16] = v;
      }
    }
  }
}

template <int K, int C, bool XH, bool DINV, bool BIAS, bool OUTH>
__global__ __launch_bounds__(256) void mfma_gemm_kernel(const void* __restrict__ Xv,
                                                        const float* __restrict__ W,
                                                        const float* __restrict__ dinv,
                                                        const float* __restrict__ bias,
                                                        void* __restrict__ G, int n) {
  __shared__ _Float16 Wt[C * (K + 8)];
  mfma_gemm_tile<K, C, XH, DINV, BIAS, OUTH>(blockIdx.x, Xv, W, dinv, bias, G, n, Wt);
}

// ---- K1: [0, nchunk) = bucket scatter chunks ; [nchunk, ...) = GEMM1 tiles ----
// Scatter: per-chunk LDS hist of coarse buckets -> one global atomicAdd per
// nonzero bucket reserves a contiguous range in that bucket's fixed-CAP slot ->
// LDS-cursor scatter writes packed (src<<7 | dst&127).  Edge-level atomics stay
// in LDS; global atomics are per-(block,bucket) only (~300K, low contention).
// GEMM1 computes x W1 UNSCALED (dinv doesn't exist yet); K2 applies the row scale.
__global__ __launch_bounds__(256) void gemm1_scatter_kernel(
    const float* __restrict__ x, const float* __restrict__ W1, __half* __restrict__ gh,
    int n, const int* __restrict__ src, const int* __restrict__ dst,
    int* __restrict__ cur0, int* __restrict__ packed, int E, int nbuck, int nchunk) {
  __shared__ __align__(16) char smem[HID * (IN_DIM + 8) * 2];  // 17408B, unioned
  const int tid = threadIdx.x;
  if ((int)blockIdx.x < nchunk) {
    int* hist = reinterpret_cast<int*>(smem);           // [MAXBUCK]
    int* cur = hist + MAXBUCK;                          // [MAXBUCK]
    for (int i = tid; i < nbuck; i += 256) hist[i] = 0;
    __syncthreads();
    const int lo = blockIdx.x * CHUNK;
    const int hi = min(E, lo + CHUNK);
    for (int i = lo + tid; i < hi; i += 256)
      atomicAdd(&hist[dst[i] >> LSHIFT], 1);
    __syncthreads();
    for (int b = tid; b < nbuck; b += 256) {
      int c = hist[b];
      cur[b] = (c > 0) ? atomicAdd(&cur0[b], c) : 0;  // reserve [base, base+c)
    }
    __syncthreads();
    for (int i = lo + tid; i < hi; i += 256) {
      int s = src[i], d = dst[i];
      int b = d >> LSHIFT;
      int off = atomicAdd(&cur[b], 1);
      if (off < CAP) packed[b * CAP + off] = (s << LSHIFT) | (d & LMASK);
    }
  } else {
    _Float16* Wt = reinterpret_cast<_Float16*>(smem);
    mfma_gemm_tile<IN_DIM, HID, false, false, false, true>(
        (int)blockIdx.x - nchunk, x, W1, nullptr, nullptr, gh, n, Wt);
  }
}

// ---- K2: one block per bucket -- the ENTIRE fine pass in one dispatch ----
// hist(128 nodes) -> bucket base = sum of already-final cur0[] -> in-block node
// prefix -> row_start + dinv -> ssrc scatter -> scale this bucket's 128 gh rows
// by dinv (bulk, coalesced -- replaces R4's per-edge dinv gathers in agg1).
__global__ __launch_bounds__(256) void fine_fused_kernel(
    const int* __restrict__ packed, const int* __restrict__ cur0,
    int* __restrict__ row_start, float* __restrict__ dinv,
    int* __restrict__ ssrc, __half* __restrict__ gh, int n, int nbuck) {
  const int b = blockIdx.x;
  const int t = threadIdx.x;
  __shared__ int hist[128];
  __shared__ int pfx[128];
  __shared__ int cur[128];
  __shared__ float sdi[128];
  __shared__ int red[4];
  __shared__ int sbase;
  if (t < 128) hist[t] = 0;
  __syncthreads();
  const int cb = min(cur0[b], CAP);
  const int* pk = &packed[(size_t)b * CAP];
  for (int e = t; e < cb; e += 256) atomicAdd(&hist[pk[e] & LMASK], 1);
  // bucket base = sum_{b'<b} min(cur0[b'], CAP)   (cur0 final since K1 completed)
  int partial = 0;
  for (int i = t; i < b; i += 256) partial += min(cur0[i], CAP);
#pragma unroll
  for (int off = 1; off < 64; off <<= 1) partial += __shfl_xor(partial, off);
  const int lane = t & 63, wv = t >> 6;
  if (lane == 0) red[wv] = partial;
  __syncthreads();  // hist + red complete
  if (t == 0) sbase = red[0] + red[1] + red[2] + red[3];
  // in-block exclusive prefix over 128 node degrees (Hillis-Steele)
  if (t < 128) pfx[t] = hist[t];
  __syncthreads();
  for (int off = 1; off < 128; off <<= 1) {
    int u = (t >= off && t < 128) ? pfx[t - off] : 0;
    __syncthreads();
    if (t < 128) pfx[t] += u;
    __syncthreads();
  }
  if (t < 128) {
    int node = b * 128 + t;
    if (node < n) {
      int rs = sbase + pfx[t] - hist[t];
      row_start[node] = rs;
      float di = 1.0f / sqrtf((float)(hist[t] + 1));  // +1 = self loop
      dinv[node] = di;
      sdi[t] = di;
      cur[t] = rs;
    } else {
      sdi[t] = 0.f;
      cur[t] = 0;
    }
  }
  if (b == nbuck - 1 && t == 0) row_start[n] = sbase + cb;  // grand total
  __syncthreads();
  // scatter this bucket's edges into ssrc
  for (int e = t; e < cb; e += 256) {
    int p = pk[e];
    int slot = atomicAdd(&cur[p & LMASK], 1);
    ssrc[slot] = p >> LSHIFT;
  }
  // scale gh rows by dinv (128 nodes x 32 half2, coalesced)
  __half2* g2 = reinterpret_cast<__half2*>(gh);
  for (int i = t; i < 128 * 32; i += 256) {
    int nd = i >> 5;
    int node = b * 128 + nd;
    if (node < n) {
      int q = i & 31;
      float2 f = __half22float2(g2[(size_t)node * 32 + q]);
      float d = sdi[nd];
      g2[(size_t)node * 32 + q] = __floats2half2_rn(f.x * d, f.y * d);
    }
  }
}

// out[d][c] = post( dinv[d]*(g[d][c] + sum_{e in row d} g[ssrc[e]][c]) [+ bias[c]] )
// g is fp16 (128B rows, 1 cache line).  One wave per node; lanes split into two
// 32-lane halves processing even/odd edges concurrently.  Each lane holds a half2
// (channels 2q, 2q+1); each gather instruction fetches two rows (256B, 2 edges).
// 8-deep unroll keeps 16 edges (4KB) in flight per wave.  fp32 accumulate; cross-
// half combine via shfl_xor(32).
template <int C, bool RELU, bool BIAS, bool TSCALE, bool OUTH>
__global__ __launch_bounds__(256) void agg_kernel(const __half* __restrict__ g,
                                                  const int* __restrict__ row_start,
                                                  const int* __restrict__ ssrc,
                                                  const float* __restrict__ dinv,
                                                  const float* __restrict__ bias,
                                                  void* __restrict__ out, int n) {
  static_assert(C == 64, "agg assumes 64 channels");
  const int tid = threadIdx.x;
  const int wv = tid >> 6;
  const int lane = tid & 63;
  const int h = lane >> 5;   // half-wave: 0 = even edges (+ self + odd tail), 1 = odd
  const int q = lane & 31;   // channel-pair index: channels {2q, 2q+1}
  int node = blockIdx.x * 4 + wv;
  if (node >= n) return;
  const __half2* g2 = reinterpret_cast<const __half2*>(g);

  int e0 = row_start[node];
  int e1 = row_start[node + 1];
  int deg = e1 - e0;
  float2 acc = make_float2(0.f, 0.f);
  if (h == 0) {  // self-loop term, counted once
    float2 sv = __half22float2(g2[(size_t)node * 32 + q]);
    acc.x = sv.x; acc.y = sv.y;
  }
  const int pairs = deg >> 1;
  const int base = e0 + h;  // this half's first edge (stride 2)
  int k = 0;
  for (; k + 8 <= pairs; k += 8) {  // 16 edges in flight per wave
    int idx[8];
#pragma unroll
    for (int i = 0; i < 8; ++i) idx[i] = ssrc[base + 2 * (k + i)];
    __half2 v[8];
#pragma unroll
    for (int i = 0; i < 8; ++i) v[i] = g2[(size_t)idx[i] * 32 + q];
#pragma unroll
    for (int i = 0; i < 8; ++i) {
      float2 f = __half22float2(v[i]);
      acc.x += f.x; acc.y += f.y;
    }
  }
  for (; k + 2 <= pairs; k += 2) {
    int i0 = ssrc[base + 2 * k];
    int i1 = ssrc[base + 2 * (k + 1)];
    float2 f0 = __half22float2(g2[(size_t)i0 * 32 + q]);
    float2 f1 = __half22float2(g2[(size_t)i1 * 32 + q]);
    acc.x += f0.x + f1.x; acc.y += f0.y + f1.y;
  }
  for (; k < pairs; ++k) {
    int i0 = ssrc[base + 2 * k];
    float2 f = __half22float2(g2[(size_t)i0 * 32 + q]);
    acc.x += f.x; acc.y += f.y;
  }
  if ((deg & 1) && h == 0) {  // odd edge handled once, by half 0
    int i0 = ssrc[e1 - 1];
    float2 f = __half22float2(g2[(size_t)i0 * 32 + q]);
    acc.x += f.x; acc.y += f.y;
  }
  // combine even/odd halves
  acc.x += __shfl_xor(acc.x, 32);
  acc.y += __shfl_xor(acc.y, 32);

  if (h == 0) {
    float di = dinv[node];
    float rx = acc.x * di, ry = acc.y * di;
    if (BIAS) {
      float2 bv = *reinterpret_cast<const float2*>(&bias[2 * q]);
      rx += bv.x; ry += bv.y;
    }
    if (RELU) { rx = fmaxf(rx, 0.f); ry = fmaxf(ry, 0.f); }
    if (TSCALE) { rx *= di; ry *= di; }
    if (OUTH) {
      reinterpret_cast<__half2*>(out)[(size_t)node * 32 + q] = __floats2half2_rn(rx, ry);
    } else {
      reinterpret_cast<float2*>(out)[(size_t)node * 32 + q] = make_float2(rx, ry);
    }
  }
}

extern "C" void kernel_launch(void* const* d_in, const int* in_sizes, int n_in,
                              void* d_out, int out_size, void* d_ws, size_t ws_size,
                              hipStream_t stream) {
  const float* x = (const float*)d_in[0];
  const int* ei = (const int*)d_in[1];
  const float* W1 = (const float*)d_in[2];
  const float* b1 = (const float*)d_in[3];
  const float* W2 = (const float*)d_in[4];
  const float* b2 = (const float*)d_in[5];
  const float* W3 = (const float*)d_in[6];
  const float* b3 = (const float*)d_in[7];
  float* out = (float*)d_out;

  const int n = in_sizes[0] / IN_DIM;  // 100000
  const int E = in_sizes[1] / 2;       // 1600000
  const int* src = ei;
  const int* dst = ei + E;
  const int nbuck = (n + LMASK) >> LSHIFT;        // 782
  const int nchunk = (E + CHUNK - 1) / CHUNK;     // 391

  char* p = (char*)d_ws;
  auto alloc = [&](size_t bytes) {
    char* q = p;
    p += (bytes + 255) & ~(size_t)255;
    return q;
  };
  float* dinv = (float*)alloc((size_t)n * 4);
  int* row_start = (int*)alloc((size_t)(n + 1) * 4);
  int* cur0 = (int*)alloc((size_t)MAXBUCK * 4);
  int* packed = (int*)alloc((size_t)nbuck * CAP * 4);
  int* ssrc = (int*)alloc((size_t)E * 4);
  __half* gh  = (__half*)alloc((size_t)n * HID * 2);  // GEMM1/2 out (gather source)
  __half* h1h = (__half*)alloc((size_t)n * HID * 2);  // agg1 out = h1 (GEMM2 in); reused as z
  __half* th  = (__half*)alloc((size_t)n * HID * 2);  // agg2 out = pre-scaled t (agg3 in)
  __half* zh  = h1h;                                   // alias: h1h dead after GEMM2

  const int GGRID = (n + 63) / 64;                 // MFMA GEMM: 64 rows/block

  // ---- dispatch 1-3: CSR build + GEMM1, 3 launches total ----
  hipMemsetAsync(cur0, 0, (size_t)MAXBUCK * 4, stream);
  gemm1_scatter_kernel<<<nchunk + GGRID, 256, 0, stream>>>(x, W1, gh, n, src, dst,
                                                           cur0, packed, E, nbuck, nchunk);
  fine_fused_kernel<<<nbuck, 256, 0, stream>>>(packed, cur0, row_start, dinv, ssrc, gh, n, nbuck);

  // ---- layer 1: h1 = relu(dinv*(gh[self] + Σ gh[s]) + b1)  (gh pre-scaled by K2) ----
  agg_kernel<HID, true, true, false, true><<<(n + 3) / 4, 256, 0, stream>>>(gh, row_start, ssrc, dinv, b1, h1h, n);

  // ---- layer 2: g2=(h1 W2)*dinv_row (fp16) ; t = relu(agg*dinv + b2)*dinv (fp16) ----
  mfma_gemm_kernel<HID, HID, true, true, false, true><<<GGRID, 256, 0, stream>>>(h1h, W2, dinv, nullptr, gh, n);
  agg_kernel<HID, true, true, true, true><<<(n + 3) / 4, 256, 0, stream>>>(gh, row_start, ssrc, dinv, b2, th, n);

  // ---- layer 3 (reordered): z = dinv*(t + Σ t[s]) (fp16) ; out = z W3 + b3 (fp32) ----
  agg_kernel<HID, false, false, false, true><<<(n + 3) / 4, 256, 0, stream>>>(th, row_start, ssrc, dinv, nullptr, zh, n);
  mfma_gemm_kernel<HID, OUT_DIM, true, false, true, false><<<GGRID, 256, 0, stream>>>(zh, W3, nullptr, b3, out, n);
}